// Round 9
// baseline (198.788 us; speedup 1.0000x reference)
//
#include <hip/hip_runtime.h>
#include <hip/hip_bf16.h>

#define IMG_W 224
#define NPIX (IMG_W * IMG_W)
#define FOCAL 500.0f
#define WARM_PTS 131072   // multiple of 4; ~71K unfiltered warm atomics

// === Round-9 ledger ===
// R8 proved: atomic SCOPE is irrelevant (rep64 workgroup-scope WRITE_SIZE
// 66919.156KB == R2 device-scope, 88us). Global atomics execute memory-side;
// ceiling ~23 far-ops/ns. Replication/scope abandoned.
// R2-R8 also proved: plain loads AFTER a kernel boundary see atomic results
// (resolve_kernel was always correct). -> warm-pass filter:
//   init (atomic stores, keeps sentinel out of local L2s)
//   warm: first 128K points, unfiltered atomicMin  (~71K far atomics)
//   main: 3.87M points, plain-load filter vs frozen warm bound (monotone-
//         safe; bound freshness guaranteed by kernel boundary), atomicMin
//         only when strictly better (~170-250K far atomics)
//   resolve: unchanged.
// Predict: warm 5-8us WRITE 2-4MB; main 15-25us WRITE 6-9MB FETCH ~50MB;
// total ~30-38us. Falsifier: main ~90us & WRITE ~60MB -> filter blind ->
// R10 tries explicit sc0 (L2-scope) filter loads.

typedef float f4 __attribute__((ext_vector_type(4)));

// Project up to 4 points starting at element `base` (base % 4 == 0).
__device__ __forceinline__ int project4(
    const float* __restrict__ pc, int n, int base,
    const float* __restrict__ cam_pos, const float* __restrict__ cam_rot,
    unsigned dbits[4], int pid[4], unsigned idx[4], bool ok[4])
{
    const float cx = cam_pos[0], cy = cam_pos[1], cz = cam_pos[2];
    const float r00 = cam_rot[0], r01 = cam_rot[1], r02 = cam_rot[2];
    const float r10 = cam_rot[3], r11 = cam_rot[4], r12 = cam_rot[5];
    const float r20 = cam_rot[6], r21 = cam_rot[7], r22 = cam_rot[8];

    if (base >= n) return 0;

    float px[4], py[4], pz[4];
    int cnt;
    if (base + 4 <= n) {
        // base%4==0 -> byte offset base*12 is 16B-aligned; 3 x float4
        const f4* pc4 = reinterpret_cast<const f4*>(pc + (size_t)base * 3);
        f4 a = __builtin_nontemporal_load(pc4 + 0);
        f4 b = __builtin_nontemporal_load(pc4 + 1);
        f4 c = __builtin_nontemporal_load(pc4 + 2);
        px[0] = a.x; py[0] = a.y; pz[0] = a.z;
        px[1] = a.w; py[1] = b.x; pz[1] = b.y;
        px[2] = b.z; py[2] = b.w; pz[2] = c.x;
        px[3] = c.y; py[3] = c.z; pz[3] = c.w;
        cnt = 4;
    } else {
        cnt = n - base;
        for (int k = 0; k < cnt; ++k) {
            px[k] = pc[(size_t)(base + k) * 3 + 0];
            py[k] = pc[(size_t)(base + k) * 3 + 1];
            pz[k] = pc[(size_t)(base + k) * 3 + 2];
        }
    }

    #pragma unroll
    for (int k = 0; k < 4; ++k) {
        ok[k] = false;
        if (k >= cnt) continue;
        const float dx = px[k] - cx, dy = py[k] - cy, dz = pz[k] - cz;
        const float zc = r20 * dx + r21 * dy + r22 * dz;
        if (!(zc > 0.1f)) continue;
        const float xc = r00 * dx + r01 * dy + r02 * dz;
        const float yc = r10 * dx + r11 * dy + r12 * dz;
        const float inv = FOCAL / zc;
        const float x = xc * inv + (float)(IMG_W / 2);
        const float y = yc * inv + (float)(IMG_W / 2);
        if (!(x >= 0.0f && x < (float)IMG_W && y >= 0.0f && y < (float)IMG_W))
            continue;
        pid[k]   = (int)y * IMG_W + (int)x;
        dbits[k] = __float_as_uint(zc);
        idx[k]   = (unsigned)(base + k);
        ok[k]    = true;
    }
    return cnt;
}

// Sentinel init via agent-scope atomic stores: bypasses local L2s, so no
// stale 0xFF lines can ever satisfy a later plain filter load.
__global__ void __launch_bounds__(256) init_zbuf(unsigned long long* zbuf)
{
    const int p = blockIdx.x * blockDim.x + threadIdx.x;
    if (p < NPIX)
        __hip_atomic_store(&zbuf[p], ~0ULL, __ATOMIC_RELAXED,
                           __HIP_MEMORY_SCOPE_AGENT);
}

// Warm pass: first WARM points, unfiltered device atomicMin.
__global__ void __launch_bounds__(256) warm_kernel(
    const float* __restrict__ pc, const float* __restrict__ cam_pos,
    const float* __restrict__ cam_rot,
    unsigned long long* __restrict__ zbuf, int n_warm)
{
    const int tid = blockIdx.x * blockDim.x + threadIdx.x;
    unsigned dbits[4]; int pid[4]; unsigned idx[4]; bool ok[4];
    if (project4(pc, n_warm, tid * 4, cam_pos, cam_rot, dbits, pid, idx, ok) == 0)
        return;
    #pragma unroll
    for (int k = 0; k < 4; ++k)
        if (ok[k]) {
            const unsigned long long pk =
                ((unsigned long long)dbits[k] << 32) | idx[k];
            atomicMin(&zbuf[pid[k]], pk);
        }
}

// Main pass: points [start, n), plain-load filter vs warm bound, then atomic.
__global__ void __launch_bounds__(256) main_kernel(
    const float* __restrict__ pc, const float* __restrict__ cam_pos,
    const float* __restrict__ cam_rot,
    unsigned long long* __restrict__ zbuf, int n, int start)
{
    const int tid = blockIdx.x * blockDim.x + threadIdx.x;
    unsigned dbits[4]; int pid[4]; unsigned idx[4]; bool ok[4];
    if (project4(pc, n, start + tid * 4, cam_pos, cam_rot, dbits, pid, idx, ok) == 0)
        return;

    // Plain cached loads of the depth word (high u32 of little-endian u64).
    // Monotone-safe: any cached value >= current true min.
    const unsigned* zb32 = reinterpret_cast<const unsigned*>(zbuf);
    unsigned seen[4];
    #pragma unroll
    for (int k = 0; k < 4; ++k)
        if (ok[k]) seen[k] = zb32[2 * pid[k] + 1];

    #pragma unroll
    for (int k = 0; k < 4; ++k)
        if (ok[k] && dbits[k] < seen[k]) {
            const unsigned long long pk =
                ((unsigned long long)dbits[k] << 32) | idx[k];
            atomicMin(&zbuf[pid[k]], pk);
        }
}

__global__ void __launch_bounds__(256) resolve_kernel(
    const unsigned long long* __restrict__ zbuf,
    const float* __restrict__ colors, float* __restrict__ out)
{
    const int p = blockIdx.x * blockDim.x + threadIdx.x;
    if (p >= NPIX) return;
    const unsigned long long m = zbuf[p];
    float cr = 0.0f, cg = 0.0f, cb = 0.0f;
    if (m != ~0ULL) {
        const unsigned idx = (unsigned)(m & 0xFFFFFFFFu);
        cr = colors[(size_t)idx * 3 + 0];
        cg = colors[(size_t)idx * 3 + 1];
        cb = colors[(size_t)idx * 3 + 2];
    }
    out[0 * NPIX + p] = cr;
    out[1 * NPIX + p] = cg;
    out[2 * NPIX + p] = cb;
}

extern "C" void kernel_launch(void* const* d_in, const int* in_sizes, int n_in,
                              void* d_out, int out_size, void* d_ws, size_t ws_size,
                              hipStream_t stream)
{
    const float* pc      = (const float*)d_in[0];
    const float* cam_pos = (const float*)d_in[1];
    const float* cam_rot = (const float*)d_in[2];
    const float* colors  = (const float*)d_in[3];
    float* out = (float*)d_out;

    const int n = in_sizes[0] / 3;
    const int n_warm = n < WARM_PTS ? (n & ~3) : WARM_PTS;

    unsigned long long* zbuf = (unsigned long long*)d_ws;  // 401 KB

    const int threads = 256;
    const int pblocks = (NPIX + threads - 1) / threads;

    init_zbuf<<<pblocks, threads, 0, stream>>>(zbuf);

    if (n_warm > 0) {
        const int wblocks = ((n_warm + 3) / 4 + threads - 1) / threads;
        warm_kernel<<<wblocks, threads, 0, stream>>>(pc, cam_pos, cam_rot,
                                                     zbuf, n_warm);
    }
    if (n > n_warm) {
        const int mthreads = (n - n_warm + 3) / 4;
        const int mblocks = (mthreads + threads - 1) / threads;
        main_kernel<<<mblocks, threads, 0, stream>>>(pc, cam_pos, cam_rot,
                                                     zbuf, n, n_warm);
    }

    resolve_kernel<<<pblocks, threads, 0, stream>>>(zbuf, colors, out);
}

// Round 10
// 162.776 us; speedup vs baseline: 1.2212x; 1.2212x over previous
//
#include <hip/hip_runtime.h>
#include <hip/hip_bf16.h>

#define IMG_W 224
#define NPIX (IMG_W * IMG_W)
#define FOCAL 500.0f
#define GRID_W 112                 // 2x2-pixel blocks
#define NGRID (GRID_W * GRID_W)    // 12544 B -> L1-resident
#define QSCALE 28.0f               // bound quantization: cell = 1/28 depth
#define W1 131072                  // warm1: unfiltered
#define W2 655360                  // warm2: filtered vs bound#1

// === Round-10 ledger ===
// Measured law (R2/R4/R8/R9): ~24 scattered lane-transactions/ns chip-wide,
// regardless of type (plain load == atomic == any scope); atomics invalidate
// L2 copies (R9 FETCH +25.6MB), so zbuf probes are far-ops too. Probing must
// therefore hit a READ-ONLY, L1-RESIDENT structure:
//   bnd[112x112] u8 = quantized-up upper bound of each 2x2 block's min depth
//   (max over 4 pixel mins, floor(z*28)+2, 255 = +inf/no-filter).
// Skip iff floor(z*28) >= bnd  =>  z >= current min  =>  can't change result
// (monotone induction as R9; quantization strictly conservative).
// Pipeline: memset -> warm1(128K unfiltered) -> bound#1 -> warm2(512K
// filtered) -> bound#2 -> main(3.36M filtered, survivors atomic directly)
// -> resolve.
// Predict: main WRITE 12-18MB (survivor readout), dur 20-30us; total 38-50us.
// Falsifiers: (a) main >=70us @ WRITE ~15MB -> probes leaving CU;
// (b) WRITE >>20MB -> bound loose, grow warm2; (c) absmax>0 -> quant bug.

typedef float f4 __attribute__((ext_vector_type(4)));

// Project up to 4 points starting at element `base` (base % 4 == 0).
// Outputs packed depth|idx candidates, pixel id, and 2x2-block cell id.
__device__ __forceinline__ int project4(
    const float* __restrict__ pc, int n, int base,
    const float* __restrict__ cam_pos, const float* __restrict__ cam_rot,
    unsigned dbits[4], int pid[4], int cell[4], unsigned idx[4], bool ok[4])
{
    const float cx = cam_pos[0], cy = cam_pos[1], cz = cam_pos[2];
    const float r00 = cam_rot[0], r01 = cam_rot[1], r02 = cam_rot[2];
    const float r10 = cam_rot[3], r11 = cam_rot[4], r12 = cam_rot[5];
    const float r20 = cam_rot[6], r21 = cam_rot[7], r22 = cam_rot[8];

    if (base >= n) return 0;

    float px[4], py[4], pz[4];
    int cnt;
    if (base + 4 <= n) {
        const f4* pc4 = reinterpret_cast<const f4*>(pc + (size_t)base * 3);
        f4 a = __builtin_nontemporal_load(pc4 + 0);
        f4 b = __builtin_nontemporal_load(pc4 + 1);
        f4 c = __builtin_nontemporal_load(pc4 + 2);
        px[0] = a.x; py[0] = a.y; pz[0] = a.z;
        px[1] = a.w; py[1] = b.x; pz[1] = b.y;
        px[2] = b.z; py[2] = b.w; pz[2] = c.x;
        px[3] = c.y; py[3] = c.z; pz[3] = c.w;
        cnt = 4;
    } else {
        cnt = n - base;
        for (int k = 0; k < cnt; ++k) {
            px[k] = pc[(size_t)(base + k) * 3 + 0];
            py[k] = pc[(size_t)(base + k) * 3 + 1];
            pz[k] = pc[(size_t)(base + k) * 3 + 2];
        }
    }

    #pragma unroll
    for (int k = 0; k < 4; ++k) {
        ok[k] = false;
        if (k >= cnt) continue;
        const float dx = px[k] - cx, dy = py[k] - cy, dz = pz[k] - cz;
        const float zc = r20 * dx + r21 * dy + r22 * dz;
        if (!(zc > 0.1f)) continue;
        const float xc = r00 * dx + r01 * dy + r02 * dz;
        const float yc = r10 * dx + r11 * dy + r12 * dz;
        const float inv = FOCAL / zc;
        const float x = xc * inv + (float)(IMG_W / 2);
        const float y = yc * inv + (float)(IMG_W / 2);
        if (!(x >= 0.0f && x < (float)IMG_W && y >= 0.0f && y < (float)IMG_W))
            continue;
        const int xi = (int)x, yi = (int)y;
        pid[k]   = yi * IMG_W + xi;
        cell[k]  = (yi >> 1) * GRID_W + (xi >> 1);
        dbits[k] = __float_as_uint(zc);
        idx[k]   = (unsigned)(base + k);
        ok[k]    = true;
    }
    return cnt;
}

// Warm1: unfiltered device atomicMin on the first W1 points.
__global__ void __launch_bounds__(256) warm1_kernel(
    const float* __restrict__ pc, const float* __restrict__ cam_pos,
    const float* __restrict__ cam_rot,
    unsigned long long* __restrict__ zbuf, int n_end)
{
    const int tid = blockIdx.x * blockDim.x + threadIdx.x;
    unsigned dbits[4]; int pid[4], cell[4]; unsigned idx[4]; bool ok[4];
    if (project4(pc, n_end, tid * 4, cam_pos, cam_rot, dbits, pid, cell, idx, ok) == 0)
        return;
    #pragma unroll
    for (int k = 0; k < 4; ++k)
        if (ok[k]) {
            const unsigned long long pk =
                ((unsigned long long)dbits[k] << 32) | idx[k];
            atomicMin(&zbuf[pid[k]], pk);
        }
}

// Build the coarse bound grid from the frozen zbuf (kernel boundary =
// coherence point, proven by 9 rounds of correct resolve reads).
// q = floor(z*28)+2 (strictly >= z*28, covers fp rounding); 255 = no-filter.
__global__ void __launch_bounds__(256) bound_build(
    const unsigned* __restrict__ zb32, unsigned char* __restrict__ bnd)
{
    const int cellid = blockIdx.x * blockDim.x + threadIdx.x;
    if (cellid >= NGRID) return;
    const int by = cellid / GRID_W, bx = cellid - by * GRID_W;
    const int p00 = (by * 2) * IMG_W + bx * 2;
    const unsigned b0 = zb32[2 * p00 + 1];
    const unsigned b1 = zb32[2 * (p00 + 1) + 1];
    const unsigned b2 = zb32[2 * (p00 + IMG_W) + 1];
    const unsigned b3 = zb32[2 * (p00 + IMG_W + 1) + 1];
    int q = 0;
    #pragma unroll
    for (int i = 0; i < 4; ++i) {
        const unsigned bits = (i == 0) ? b0 : (i == 1) ? b1 : (i == 2) ? b2 : b3;
        const float zq = __uint_as_float(bits) * QSCALE;
        // NaN (0xFFFFFFFF sentinel) and zq >= 253 both -> 255 (no-filter)
        const int qi = (zq < 253.0f) ? ((int)zq + 2) : 255;
        q = qi > q ? qi : q;
    }
    bnd[cellid] = (unsigned char)q;
}

// Filtered pass: probe the L1-resident bound grid; survivors atomic directly.
__global__ void __launch_bounds__(256) filtered_kernel(
    const float* __restrict__ pc, const float* __restrict__ cam_pos,
    const float* __restrict__ cam_rot,
    unsigned long long* __restrict__ zbuf,
    const unsigned char* __restrict__ bnd, int n_end, int start)
{
    const int tid = blockIdx.x * blockDim.x + threadIdx.x;
    unsigned dbits[4]; int pid[4], cell[4]; unsigned idx[4]; bool ok[4];
    if (project4(pc, n_end, start + tid * 4, cam_pos, cam_rot,
                 dbits, pid, cell, idx, ok) == 0)
        return;

    #pragma unroll
    for (int k = 0; k < 4; ++k) {
        if (!ok[k]) continue;
        const int b = (int)bnd[cell[k]];          // L1-resident u8 probe
        const float zq = __uint_as_float(dbits[k]) * QSCALE;
        const int qd = (zq < 255.0f) ? (int)zq : 255;
        if (b == 255 || qd < b) {                  // skip iff qd >= b (b<255)
            const unsigned long long pk =
                ((unsigned long long)dbits[k] << 32) | idx[k];
            atomicMin(&zbuf[pid[k]], pk);
        }
    }
}

__global__ void __launch_bounds__(256) resolve_kernel(
    const unsigned long long* __restrict__ zbuf,
    const float* __restrict__ colors, float* __restrict__ out)
{
    const int p = blockIdx.x * blockDim.x + threadIdx.x;
    if (p >= NPIX) return;
    const unsigned long long m = zbuf[p];
    float cr = 0.0f, cg = 0.0f, cb = 0.0f;
    if (m != ~0ULL) {
        const unsigned idx = (unsigned)(m & 0xFFFFFFFFu);
        cr = colors[(size_t)idx * 3 + 0];
        cg = colors[(size_t)idx * 3 + 1];
        cb = colors[(size_t)idx * 3 + 2];
    }
    out[0 * NPIX + p] = cr;
    out[1 * NPIX + p] = cg;
    out[2 * NPIX + p] = cb;
}

extern "C" void kernel_launch(void* const* d_in, const int* in_sizes, int n_in,
                              void* d_out, int out_size, void* d_ws, size_t ws_size,
                              hipStream_t stream)
{
    const float* pc      = (const float*)d_in[0];
    const float* cam_pos = (const float*)d_in[1];
    const float* cam_rot = (const float*)d_in[2];
    const float* colors  = (const float*)d_in[3];
    float* out = (float*)d_out;

    const int n = in_sizes[0] / 3;
    const int threads = 256;
    const int pblocks = (NPIX + threads - 1) / threads;

    unsigned long long* zbuf = (unsigned long long*)d_ws;          // 401,408 B
    unsigned char* bnd = (unsigned char*)d_ws + (size_t)NPIX * 8;  // 12,544 B

    hipMemsetAsync(zbuf, 0xFF, (size_t)NPIX * 8, stream);

    const int e1 = n < W1 ? n : W1;
    const int e2 = n < W2 ? n : W2;

    if (e1 > 0) {
        const int b1 = ((e1 + 3) / 4 + threads - 1) / threads;
        warm1_kernel<<<b1, threads, 0, stream>>>(pc, cam_pos, cam_rot, zbuf, e1);
    }
    const int gblocks = (NGRID + threads - 1) / threads;
    bound_build<<<gblocks, threads, 0, stream>>>((const unsigned*)zbuf, bnd);

    if (e2 > e1) {
        const int b2 = ((e2 - e1 + 3) / 4 + threads - 1) / threads;
        filtered_kernel<<<b2, threads, 0, stream>>>(pc, cam_pos, cam_rot,
                                                    zbuf, bnd, e2, e1);
        bound_build<<<gblocks, threads, 0, stream>>>((const unsigned*)zbuf, bnd);
    }
    if (n > e2) {
        const int b3 = ((n - e2 + 3) / 4 + threads - 1) / threads;
        filtered_kernel<<<b3, threads, 0, stream>>>(pc, cam_pos, cam_rot,
                                                    zbuf, bnd, n, e2);
    }

    resolve_kernel<<<pblocks, threads, 0, stream>>>(zbuf, colors, out);
}